// Round 3
// baseline (183.802 us; speedup 1.0000x reference)
//
#include <hip/hip_runtime.h>
#include <stdint.h>

#define BSH (32 * 128 * 128)

typedef __attribute__((ext_vector_type(8))) __bf16 bf16x8;
typedef __attribute__((ext_vector_type(4))) float f32x4;

__device__ __forceinline__ unsigned short f2bf(float f) {
  union { float f; unsigned u; } v; v.f = f;
  return (unsigned short)((v.u + 0x7FFFu + ((v.u >> 16) & 1u)) >> 16);
}

__device__ __forceinline__ float fast_exp2(float x) {
#if __has_builtin(__builtin_amdgcn_exp2f)
  return __builtin_amdgcn_exp2f(x);
#else
  float r; asm("v_exp_f32 %0, %1" : "=v"(r) : "v"(x)); return r;
#endif
}
__device__ __forceinline__ float fast_rcp(float x) {
#if __has_builtin(__builtin_amdgcn_rcpf)
  return __builtin_amdgcn_rcpf(x);
#else
  float r; asm("v_rcp_f32 %0, %1" : "=v"(r) : "v"(x)); return r;
#endif
}

// tanh-form GELU (MLP path; ~3e-3 max err vs exact erf GELU).
__device__ __forceinline__ float gelu_f(float y) {
  float u = y * y;
  float p = __builtin_fmaf(u, 0.044715f, 1.0f) * y;
  float w = fast_exp2(p * 2.30220787f);
  return y - y * fast_rcp(1.0f + w);
}

// ---------------------------------------------------------------------------
// Chunked k-major layout: tensor [row][k] stored as chunk(kq,row) =
// base + (kq*128 + row)*8 bf16 (16 B). MFMA fragment read = one
// global_load_dwordx4, 256 B contiguous per quad.
// ---------------------------------------------------------------------------
__device__ __forceinline__ void transpose_part(const float* __restrict__ src,
                                               unsigned short* __restrict__ dst,
                                               unsigned short* lds, int part) {
  const int tid = threadIdx.x;
  const float4* s4 = (const float4*)(src) + part * 1024;
  __syncthreads();  // protect LDS reuse across sequential calls
#pragma unroll
  for (int it = 0; it < 4; ++it) {
    int i4 = tid + it * 256;       // local float4 idx; row s = i4>>5 in 0..31
    float4 v = s4[i4];
    int s = i4 >> 5;
    int t0 = (i4 * 4) & 127;
    unsigned short t[4] __attribute__((aligned(8)));
    t[0] = f2bf(v.x); t[1] = f2bf(v.y); t[2] = f2bf(v.z); t[3] = f2bf(v.w);
    *(uint2*)(lds + s * 136 + t0) = *(const uint2*)t;  // 272B pitch: 8B-aligned
  }
  __syncthreads();
#pragma unroll
  for (int it = 0; it < 2; ++it) {
    int c = tid + it * 256;        // kq_local = c>>7 (0..3), tr = c&127
    int kql = c >> 7, tr = c & 127;
    unsigned short tmp[8] __attribute__((aligned(16)));
#pragma unroll
    for (int e = 0; e < 8; ++e) tmp[e] = lds[(kql * 8 + e) * 136 + tr];
    *(uint4*)(dst + ((part * 4 + kql) * 128 + tr) * 8) = *(const uint4*)tmp;
  }
}

// grid = 1024 (W1, 4 parts x 256 tiles) + 128 (trend2, 4 parts x 32) + 2 (Wm).
__global__ __launch_bounds__(256) void prepass_kernel(
    const float* __restrict__ W1, const float* __restrict__ trend2,
    const float* __restrict__ Wm1, const float* __restrict__ Wm2,
    unsigned short* __restrict__ W1Tc, unsigned short* __restrict__ T2c,
    unsigned short* __restrict__ Wm1c, unsigned short* __restrict__ Wm2c,
    float* __restrict__ out2) {
  __shared__ __align__(16) unsigned short lds[32 * 136];
  const int bid = blockIdx.x;
  if (bid < 1024) {  // W1[stage][j][s][t] -> chunks (kq_s, t), XCD-pinned j map
    int part = bid >> 8, w = bid & 255;
    int x = w & 7, i = w >> 3;       // i 0..31
    int stage = i >> 4, u = i & 15;  // u 0..15
    int m = u & 7, half = u >> 3;
    int jpp = x + 8 * m;             // pair index owned by XCD x
    int j = half ? 127 - jpp : jpp;
    int blk = stage * 128 + j;
    transpose_part(W1 + blk * 16384, W1Tc + blk * 16384, lds, part);
  } else if (bid < 1152) {  // trend2[b][s][h] -> chunks (kq_s, h) + fp32 copy
    int t = bid - 1024;
    int part = t >> 5, b = t & 31;
    transpose_part(trend2 + b * 16384, T2c + b * 16384, lds, part);
    const float4* s4 = (const float4*)(trend2 + b * 16384);
    float4* d4 = (float4*)(out2 + b * 16384);
#pragma unroll
    for (int it = 0; it < 4; ++it) {
      int i = part * 1024 + threadIdx.x + it * 256;
      d4[i] = s4[i];
    }
  } else if (bid == 1152) {
#pragma unroll
    for (int part = 0; part < 4; ++part)
      transpose_part(Wm1, Wm1c, lds, part);
  } else {
#pragma unroll
    for (int part = 0; part < 4; ++part)
      transpose_part(Wm2, Wm2c, lds, part);
  }
}

// ---------------------------------------------------------------------------
// Fused mix + row-wise output MLP (unchanged from R2 — this round is a
// TIMING PROBE: stage-1 mix is launched 3x (idempotent) so that
// dur_delta = 2 x mix-dispatch-duration, resolving whether our kernels or
// the harness floor dominate the 140 us.
// ---------------------------------------------------------------------------
__global__ __launch_bounds__(256, 3) void mix_mlp_kernel(
    const unsigned short* __restrict__ XTc,   // [32] chunks (kq_s, h)
    const unsigned short* __restrict__ W1Tj,  // [128] chunks (kq_s, t), stage
    const float* __restrict__ b1j,            // [128][128] (j, t)
    const float* __restrict__ W2j,            // [128][128] (j, t)
    const float* __restrict__ b2j,            // [128]
    const float* __restrict__ trendR,         // [32][128][128] fp32 residual
    const unsigned short* __restrict__ Wm1c,  // chunks (kq_in, out)
    const unsigned short* __restrict__ Wm2c,  // chunks (kq_in, out)
    const float* __restrict__ bm1,
    const float* __restrict__ bm2,
    float* __restrict__ outA,                 // [32][128][128] fp32 MLP out
    unsigned short* __restrict__ outTc) {     // optional chunks (kq_s, h)
  __shared__ float res[512];
  __shared__ __align__(16) float xrow[2][128];
  __shared__ __align__(16) unsigned short urow[2][128];
  const int bid = blockIdx.x;
  const int b = bid >> 6;
  const int jp = bid & 63;       // bid&7 = jp&7 -> XCD pin matches prepass
  const int js = jp, jb = 127 - jp;
  const int tid = threadIdx.x;
  const int wave = tid >> 6;     // wave = 2*mh + p
  const int p = wave & 1;        // h-half
  const int mh = wave >> 1;      // mt parity
  const int lane = tid & 63;
  const int lane15 = lane & 15;
  const int quad = lane >> 4;

  const int nt_s = (js >> 4) + 1;  // m-tiles (real work; t>j rows are zeros)
  const int nt_b = (jb >> 4) + 1;

  const unsigned short* Bp = XTc + b * 16384 + (p * 64 + lane15) * 8;
  const unsigned short* As = W1Tj + js * 16384 + lane15 * 8;
  const unsigned short* Ab = W1Tj + jb * 16384 + lane15 * 8;
  const float C = -2.45546937f;  // -1.702 * log2(e)

  // ---- hoist B-fragments into registers, once, branchless (full tile) ----
  bf16x8 Bv[4][4];
#pragma unroll
  for (int ks = 0; ks < 4; ++ks) {
    const int ko = (ks * 4 + quad) * 1024;
    Bv[ks][0] = *(const bf16x8*)(Bp + ko);
    Bv[ks][1] = *(const bf16x8*)(Bp + ko + 128);
    Bv[ks][2] = *(const bf16x8*)(Bp + ko + 256);
    Bv[ks][3] = *(const bf16x8*)(Bp + ko + 384);
  }

  float psum[2][4];
#pragma unroll
  for (int jj = 0; jj < 2; ++jj)
#pragma unroll
    for (int ni = 0; ni < 4; ++ni) psum[jj][ni] = 0.f;

  // ---- pass 1: big j (jb), this wave's mt-parity, ks unconditional ----
  for (int mt = mh; mt < nt_b; mt += 2) {
    const int mo = mt * 128;
    bf16x8 a[4];
#pragma unroll
    for (int ks = 0; ks < 4; ++ks)
      a[ks] = *(const bf16x8*)(Ab + (ks * 4 + quad) * 1024 + mo);
    const int tb = mt * 16 + quad * 4;
    float4 b1v = *(const float4*)(b1j + jb * 128 + tb);
    float4 w2v = *(const float4*)(W2j + jb * 128 + tb);
    f32x4 acc[4];
#pragma unroll
    for (int ni = 0; ni < 4; ++ni) { f32x4 z = {0.f, 0.f, 0.f, 0.f}; acc[ni] = z; }
#pragma unroll
    for (int ks = 0; ks < 4; ++ks) {
      acc[0] = __builtin_amdgcn_mfma_f32_16x16x32_bf16(a[ks], Bv[ks][0], acc[0], 0, 0, 0);
      acc[1] = __builtin_amdgcn_mfma_f32_16x16x32_bf16(a[ks], Bv[ks][1], acc[1], 0, 0, 0);
      acc[2] = __builtin_amdgcn_mfma_f32_16x16x32_bf16(a[ks], Bv[ks][2], acc[2], 0, 0, 0);
      acc[3] = __builtin_amdgcn_mfma_f32_16x16x32_bf16(a[ks], Bv[ks][3], acc[3], 0, 0, 0);
    }
#pragma unroll
    for (int r = 0; r < 4; ++r) {
      float b1r = ((const float*)&b1v)[r];
      float w2r = ((const float*)&w2v)[r];
      float cb = C * b1r;
      float bw = b1r * w2r;
#pragma unroll
      for (int ni = 0; ni < 4; ++ni) {
        float av = acc[ni][r];
        float m = __builtin_fmaf(av, C, cb);
        float e = fast_exp2(m);
        float rr2 = fast_rcp(1.0f + e);
        float yw = __builtin_fmaf(av, w2r, bw);
        psum[1][ni] = __builtin_fmaf(yw, rr2, psum[1][ni]);
      }
    }
  }

  // ---- pass 2: small j (js), B already in registers, ks unconditional ----
  for (int mt = mh; mt < nt_s; mt += 2) {
    const int mo = mt * 128;
    bf16x8 a[2];
#pragma unroll
    for (int ks = 0; ks < 2; ++ks)
      a[ks] = *(const bf16x8*)(As + (ks * 4 + quad) * 1024 + mo);
    const int tb = mt * 16 + quad * 4;
    float4 b1v = *(const float4*)(b1j + js * 128 + tb);
    float4 w2v = *(const float4*)(W2j + js * 128 + tb);
    f32x4 acc[4];
#pragma unroll
    for (int ni = 0; ni < 4; ++ni) { f32x4 z = {0.f, 0.f, 0.f, 0.f}; acc[ni] = z; }
#pragma unroll
    for (int ks = 0; ks < 2; ++ks) {
      acc[0] = __builtin_amdgcn_mfma_f32_16x16x32_bf16(a[ks], Bv[ks][0], acc[0], 0, 0, 0);
      acc[1] = __builtin_amdgcn_mfma_f32_16x16x32_bf16(a[ks], Bv[ks][1], acc[1], 0, 0, 0);
      acc[2] = __builtin_amdgcn_mfma_f32_16x16x32_bf16(a[ks], Bv[ks][2], acc[2], 0, 0, 0);
      acc[3] = __builtin_amdgcn_mfma_f32_16x16x32_bf16(a[ks], Bv[ks][3], acc[3], 0, 0, 0);
    }
#pragma unroll
    for (int r = 0; r < 4; ++r) {
      float b1r = ((const float*)&b1v)[r];
      float w2r = ((const float*)&w2v)[r];
      float cb = C * b1r;
      float bw = b1r * w2r;
#pragma unroll
      for (int ni = 0; ni < 4; ++ni) {
        float av = acc[ni][r];
        float m = __builtin_fmaf(av, C, cb);
        float e = fast_exp2(m);
        float rr2 = fast_rcp(1.0f + e);
        float yw = __builtin_fmaf(av, w2r, bw);
        psum[0][ni] = __builtin_fmaf(yw, rr2, psum[0][ni]);
      }
    }
  }

  // quad reduction (sum over the 4 t-rows held across quads)
#pragma unroll
  for (int jj = 0; jj < 2; ++jj)
#pragma unroll
    for (int ni = 0; ni < 4; ++ni) {
      float v = psum[jj][ni];
      v += __shfl_xor(v, 16, 64);
      v += __shfl_xor(v, 32, 64);
      psum[jj][ni] = v;
    }

  // cross-wave (mt-parity) combine via LDS: idx = wave*128 + jj*64 + ni*16 + l
  if (quad == 0) {
#pragma unroll
    for (int jj = 0; jj < 2; ++jj)
#pragma unroll
      for (int ni = 0; ni < 4; ++ni)
        res[wave * 128 + jj * 64 + ni * 16 + lane15] = psum[jj][ni];
  }
  __syncthreads();
  {
    // tid = p*128 + jj*64 + ni*16 + l  ->  partner at tid + 256 (mh=1)
    const int l = tid & 15;
    const int nni = (tid >> 4) & 3;
    const int jj = (tid >> 6) & 1;
    const int pp = tid >> 7;
    const int j = jj ? jb : js;
    const int h = pp * 64 + nni * 16 + l;
    float v = res[tid] + res[tid + 256] + b2j[j] +
              trendR[(b * 128 + j) * 128 + h];
    xrow[jj][h] = v;  // bijective tid -> (jj, h); x rows stay on-chip
  }
  __syncthreads();

  // ---- fused MLP: rows x[js], x[jb] -> gelu(x@Wm1+bm1)@Wm2+bm2 ----
  // A-frag rows 0..15 = x[lane15 & 1]; only D rows 0,1 are consumed.
  const int arow = lane15 & 1;
  bf16x8 af[4];
#pragma unroll
  for (int ks = 0; ks < 4; ++ks) {
    const f32x4* xp = (const f32x4*)&xrow[arow][(ks * 4 + quad) * 8];
    f32x4 v0 = xp[0], v1 = xp[1];
    unsigned short t[8] __attribute__((aligned(16)));
    t[0] = f2bf(v0[0]); t[1] = f2bf(v0[1]); t[2] = f2bf(v0[2]); t[3] = f2bf(v0[3]);
    t[4] = f2bf(v1[0]); t[5] = f2bf(v1[1]); t[6] = f2bf(v1[2]); t[7] = f2bf(v1[3]);
    af[ks] = *(const bf16x8*)t;
  }
  f32x4 acc1[2];
  { f32x4 z = {0.f, 0.f, 0.f, 0.f}; acc1[0] = z; acc1[1] = z; }
#pragma unroll
  for (int ks = 0; ks < 4; ++ks) {  // GEMM1: x @ Wm1 (cols wave*32..+31)
    int kq = ks * 4 + quad;
    bf16x8 w0 = *(const bf16x8*)(Wm1c + (kq * 128 + wave * 32 + lane15) * 8);
    bf16x8 w1 = *(const bf16x8*)(Wm1c + (kq * 128 + wave * 32 + 16 + lane15) * 8);
    acc1[0] = __builtin_amdgcn_mfma_f32_16x16x32_bf16(af[ks], w0, acc1[0], 0, 0, 0);
    acc1[1] = __builtin_amdgcn_mfma_f32_16x16x32_bf16(af[ks], w1, acc1[1], 0, 0, 0);
  }
  if (quad == 0) {  // D rows 0,1 live in quad 0, regs 0,1
#pragma unroll
    for (int ni2 = 0; ni2 < 2; ++ni2) {
      int n = wave * 32 + ni2 * 16 + lane15;
      float bv = bm1[n];
      urow[0][n] = f2bf(gelu_f(acc1[ni2][0] + bv));
      urow[1][n] = f2bf(gelu_f(acc1[ni2][1] + bv));
    }
  }
  __syncthreads();
  bf16x8 uf[4];
#pragma unroll
  for (int ks = 0; ks < 4; ++ks)  // A-frag rebuild from LDS (16B aligned)
    uf[ks] = *(const bf16x8*)&urow[arow][(ks * 4 + quad) * 8];
  f32x4 acc2[2];
  { f32x4 z = {0.f, 0.f, 0.f, 0.f}; acc2[0] = z; acc2[1] = z; }
#pragma unroll
  for (int ks = 0; ks < 4; ++ks) {  // GEMM2: u @ Wm2
    int kq = ks * 4 + quad;
    bf16x8 w0 = *(const bf16x8*)(Wm2c + (kq * 128 + wave * 32 + lane15) * 8);
    bf16x8 w1 = *(const bf16x8*)(Wm2c + (kq * 128 + wave * 32 + 16 + lane15) * 8);
    acc2[0] = __builtin_amdgcn_mfma_f32_16x16x32_bf16(uf[ks], w0, acc2[0], 0, 0, 0);
    acc2[1] = __builtin_amdgcn_mfma_f32_16x16x32_bf16(uf[ks], w1, acc2[1], 0, 0, 0);
  }
  if (quad == 0) {
#pragma unroll
    for (int ni2 = 0; ni2 < 2; ++ni2) {
      int n = wave * 32 + ni2 * 16 + lane15;
      float bv = bm2[n];
#pragma unroll
      for (int r = 0; r < 2; ++r) {
        int j = r ? jb : js;
        float v = acc2[ni2][r] + bv;
        outA[(b * 128 + j) * 128 + n] = v;
        if (outTc)  // chunks (kq_s, h) feeding the next stage's B-operand
          outTc[b * 16384 + ((j >> 3) * 128 + n) * 8 + (j & 7)] = f2bf(v);
      }
    }
  }
}

// ---------------------------------------------------------------------------
extern "C" void kernel_launch(void* const* d_in, const int* in_sizes, int n_in,
                              void* d_out, int out_size, void* d_ws, size_t ws_size,
                              hipStream_t stream) {
  (void)in_sizes; (void)n_in; (void)out_size; (void)ws_size;
  const float* trend0 = (const float*)d_in[0];
  const float* trend1 = (const float*)d_in[1];
  const float* trend2 = (const float*)d_in[2];
  const float* W1  = (const float*)d_in[3];
  const float* b1  = (const float*)d_in[4];
  const float* W2  = (const float*)d_in[5];
  const float* b2  = (const float*)d_in[6];
  const float* Wm1 = (const float*)d_in[7];
  const float* bm1 = (const float*)d_in[8];
  const float* Wm2 = (const float*)d_in[9];
  const float* bm2 = (const float*)d_in[10];
  float* out = (float*)d_out;
  char* ws = (char*)d_ws;

  unsigned short* W1Tc = (unsigned short*)(ws);             // 8.39 MB (2 stages)
  unsigned short* T2c  = (unsigned short*)(ws + 8388608);   // 1 MB
  unsigned short* A1Tc = (unsigned short*)(ws + 9437184);   // 1 MB
  unsigned short* Wm1c = (unsigned short*)(ws + 10485760);  // 32 KB
  unsigned short* Wm2c = (unsigned short*)(ws + 10518528);  // 32 KB

  // outputs: [A2 | A1 | trend2]
  prepass_kernel<<<1154, 256, 0, stream>>>(W1, trend2, Wm1, Wm2,
                                           W1Tc, T2c, Wm1c, Wm2c, out + 2 * BSH);
  // stage 0: X = trend2, residual = trend1 -> A1 (fp32 out + chunks for stage1)
  mix_mlp_kernel<<<2048, 256, 0, stream>>>(T2c, W1Tc, b1, W2, b2, trend1,
                                           Wm1c, Wm2c, bm1, bm2,
                                           out + BSH, A1Tc);
  // stage 1: X = A1, residual = trend0 -> A2 (fp32 out only)
  // PROBE: launched 3x (idempotent). dur_delta vs R2 = 2x one mix dispatch.
  mix_mlp_kernel<<<2048, 256, 0, stream>>>(A1Tc, W1Tc + 128 * 16384, b1 + 16384,
                                           W2 + 16384, b2 + 128, trend0,
                                           Wm1c, Wm2c, bm1, bm2,
                                           out, (unsigned short*)nullptr);
  mix_mlp_kernel<<<2048, 256, 0, stream>>>(A1Tc, W1Tc + 128 * 16384, b1 + 16384,
                                           W2 + 16384, b2 + 128, trend0,
                                           Wm1c, Wm2c, bm1, bm2,
                                           out, (unsigned short*)nullptr);
  mix_mlp_kernel<<<2048, 256, 0, stream>>>(A1Tc, W1Tc + 128 * 16384, b1 + 16384,
                                           W2 + 16384, b2 + 128, trend0,
                                           Wm1c, Wm2c, bm1, bm2,
                                           out, (unsigned short*)nullptr);
}

// Round 5
// 145.866 us; speedup vs baseline: 1.2601x; 1.2601x over previous
//
#include <hip/hip_runtime.h>
#include <stdint.h>

#define BSH (32 * 128 * 128)

typedef __attribute__((ext_vector_type(8))) __bf16 bf16x8;
typedef __attribute__((ext_vector_type(4))) float f32x4;

__device__ __forceinline__ unsigned short f2bf(float f) {
  union { float f; unsigned u; } v; v.f = f;
  return (unsigned short)((v.u + 0x7FFFu + ((v.u >> 16) & 1u)) >> 16);
}

__device__ __forceinline__ float fast_exp2(float x) {
#if __has_builtin(__builtin_amdgcn_exp2f)
  return __builtin_amdgcn_exp2f(x);
#else
  float r; asm("v_exp_f32 %0, %1" : "=v"(r) : "v"(x)); return r;
#endif
}
__device__ __forceinline__ float fast_rcp(float x) {
#if __has_builtin(__builtin_amdgcn_rcpf)
  return __builtin_amdgcn_rcpf(x);
#else
  float r; asm("v_rcp_f32 %0, %1" : "=v"(r) : "v"(x)); return r;
#endif
}

// tanh-form GELU (MLP path; ~3e-3 max err vs exact erf GELU).
__device__ __forceinline__ float gelu_f(float y) {
  float u = y * y;
  float p = __builtin_fmaf(u, 0.044715f, 1.0f) * y;
  float w = fast_exp2(p * 2.30220787f);
  return y - y * fast_rcp(1.0f + w);
}

// ---------------------------------------------------------------------------
// Chunked k-major layout: tensor [row][k] stored as chunk(kq,row) =
// base + (kq*128 + row)*8 bf16 (16 B). MFMA fragment read = one
// global_load_dwordx4, 256 B contiguous per quad.
// ---------------------------------------------------------------------------
__device__ __forceinline__ void transpose_part(const float* __restrict__ src,
                                               unsigned short* __restrict__ dst,
                                               unsigned short* lds, int part) {
  const int tid = threadIdx.x;
  const float4* s4 = (const float4*)(src) + part * 1024;
  __syncthreads();  // protect LDS reuse across sequential calls
#pragma unroll
  for (int it = 0; it < 4; ++it) {
    int i4 = tid + it * 256;       // local float4 idx; row s = i4>>5 in 0..31
    float4 v = s4[i4];
    int s = i4 >> 5;
    int t0 = (i4 * 4) & 127;
    unsigned short t[4] __attribute__((aligned(8)));
    t[0] = f2bf(v.x); t[1] = f2bf(v.y); t[2] = f2bf(v.z); t[3] = f2bf(v.w);
    *(uint2*)(lds + s * 136 + t0) = *(const uint2*)t;  // 272B pitch: 8B-aligned
  }
  __syncthreads();
#pragma unroll
  for (int it = 0; it < 2; ++it) {
    int c = tid + it * 256;        // kq_local = c>>7 (0..3), tr = c&127
    int kql = c >> 7, tr = c & 127;
    unsigned short tmp[8] __attribute__((aligned(16)));
#pragma unroll
    for (int e = 0; e < 8; ++e) tmp[e] = lds[(kql * 8 + e) * 136 + tr];
    *(uint4*)(dst + ((part * 4 + kql) * 128 + tr) * 8) = *(const uint4*)tmp;
  }
}

// XCD owner of tile j is ((min(j,127-j))>>2)&7 — matches mix grid 512 where
// bid = b*16 + jg, bid&7 = jg&7 (16b ≡ 0 mod 8). Inverse map below: for
// owner x, jp spans {4x..4x+3} ∪ {4x+32..4x+35} via m = 0..7.
__global__ __launch_bounds__(256) void prepass_kernel(
    const float* __restrict__ W1, const float* __restrict__ trend2,
    const float* __restrict__ Wm1, const float* __restrict__ Wm2,
    unsigned short* __restrict__ W1Tc, unsigned short* __restrict__ T2c,
    unsigned short* __restrict__ Wm1c, unsigned short* __restrict__ Wm2c,
    float* __restrict__ out2) {
  __shared__ __align__(16) unsigned short lds[32 * 136];
  const int bid = blockIdx.x;
  if (bid < 1024) {  // W1[stage][j][s][t] -> chunks (kq_s, t), XCD-pinned j map
    int part = bid >> 8, w = bid & 255;
    int x = w & 7, i = w >> 3;       // i 0..31
    int stage = i >> 4, u = i & 15;  // u 0..15
    int m = u & 7, half = u >> 3;
    int jpp = 4 * x + (m & 3) + 32 * (m >> 2);  // jp owned by XCD x (jg&7==x)
    int j = half ? 127 - jpp : jpp;
    int blk = stage * 128 + j;
    transpose_part(W1 + blk * 16384, W1Tc + blk * 16384, lds, part);
  } else if (bid < 1152) {  // trend2[b][s][h] -> chunks (kq_s, h) + fp32 copy
    int t = bid - 1024;
    int part = t >> 5, b = t & 31;
    transpose_part(trend2 + b * 16384, T2c + b * 16384, lds, part);
    const float4* s4 = (const float4*)(trend2 + b * 16384);
    float4* d4 = (float4*)(out2 + b * 16384);
#pragma unroll
    for (int it = 0; it < 4; ++it) {
      int i = part * 1024 + threadIdx.x + it * 256;
      d4[i] = s4[i];
    }
  } else if (bid == 1152) {
#pragma unroll
    for (int part = 0; part < 4; ++part)
      transpose_part(Wm1, Wm1c, lds, part);
  } else {
#pragma unroll
    for (int part = 0; part < 4; ++part)
      transpose_part(Wm2, Wm2c, lds, part);
  }
}

// ---------------------------------------------------------------------------
// Mix+MLP v2: j-GROUP blocks. Grid 512 = 32 b x 16 jg; each block owns 4
// j-pairs (8 j values). Rationale (R3 probe): mix was latency-bound, not
// throughput-bound (R1/R2 instruction-count changes were neutral; models say
// 6-8 us vs 22 us measured). B depends only on b, so one block amortizes the
// 16-load B-hoist prologue, the reduce/LDS bounce, and the ENTIRE 3-barrier
// MLP tail over 4x the work; grid 512 = 2 blocks/CU, all co-resident (one
// occupancy round). psum reduced + stashed per-g so register peak stays flat.
// ---------------------------------------------------------------------------
__global__ __launch_bounds__(256, 3) void mix_mlp_kernel(
    const unsigned short* __restrict__ XTc,   // [32] chunks (kq_s, h)
    const unsigned short* __restrict__ W1Tj,  // [128] chunks (kq_s, t), stage
    const float* __restrict__ b1j,            // [128][128] (j, t)
    const float* __restrict__ W2j,            // [128][128] (j, t)
    const float* __restrict__ b2j,            // [128]
    const float* __restrict__ trendR,         // [32][128][128] fp32 residual
    const unsigned short* __restrict__ Wm1c,  // chunks (kq_in, out)
    const unsigned short* __restrict__ Wm2c,  // chunks (kq_in, out)
    const float* __restrict__ bm1,
    const float* __restrict__ bm2,
    float* __restrict__ outA,                 // [32][128][128] fp32 MLP out
    unsigned short* __restrict__ outTc) {     // optional chunks (kq_s, h)
  __shared__ float res[4 * 512];                       // per-g bounce
  __shared__ __align__(16) float xrow[8][128];         // 8 finished x rows
  __shared__ __align__(16) unsigned short urow[8][128];
  const int bid = blockIdx.x;
  const int b = bid >> 4;
  const int jg = bid & 15;       // bid&7 = jg&7 -> XCD pin matches prepass
  const int tid = threadIdx.x;
  const int wave = tid >> 6;     // wave = 2*mh + p
  const int p = wave & 1;        // h-half
  const int mh = wave >> 1;      // mt parity
  const int lane = tid & 63;
  const int lane15 = lane & 15;
  const int quad = lane >> 4;

  const unsigned short* Bp = XTc + b * 16384 + (p * 64 + lane15) * 8;
  const float C = -2.45546937f;  // -1.702 * log2(e)

  // ---- hoist B-fragments into registers, ONCE per block (b-invariant) ----
  bf16x8 Bv[4][4];
#pragma unroll
  for (int ks = 0; ks < 4; ++ks) {
    const int ko = (ks * 4 + quad) * 1024;
    Bv[ks][0] = *(const bf16x8*)(Bp + ko);
    Bv[ks][1] = *(const bf16x8*)(Bp + ko + 128);
    Bv[ks][2] = *(const bf16x8*)(Bp + ko + 256);
    Bv[ks][3] = *(const bf16x8*)(Bp + ko + 384);
  }

  // ---- 4 j-pairs per block ----
  for (int g = 0; g < 4; ++g) {
    const int jp = jg * 4 + g;
    const int js = jp, jb = 127 - jp;
    const int nt_s = (js >> 4) + 1;
    const int nt_b = (jb >> 4) + 1;
    const unsigned short* As = W1Tj + js * 16384 + lane15 * 8;
    const unsigned short* Ab = W1Tj + jb * 16384 + lane15 * 8;

    float psum[2][4];
#pragma unroll
    for (int jj = 0; jj < 2; ++jj)
#pragma unroll
      for (int ni = 0; ni < 4; ++ni) psum[jj][ni] = 0.f;

    // pass 1: big j (jb), this wave's mt-parity, ks unconditional
    for (int mt = mh; mt < nt_b; mt += 2) {
      const int mo = mt * 128;
      bf16x8 a[4];
#pragma unroll
      for (int ks = 0; ks < 4; ++ks)
        a[ks] = *(const bf16x8*)(Ab + (ks * 4 + quad) * 1024 + mo);
      const int tb = mt * 16 + quad * 4;
      float4 b1v = *(const float4*)(b1j + jb * 128 + tb);
      float4 w2v = *(const float4*)(W2j + jb * 128 + tb);
      f32x4 acc[4];
#pragma unroll
      for (int ni = 0; ni < 4; ++ni) { f32x4 z = {0.f, 0.f, 0.f, 0.f}; acc[ni] = z; }
#pragma unroll
      for (int ks = 0; ks < 4; ++ks) {
        acc[0] = __builtin_amdgcn_mfma_f32_16x16x32_bf16(a[ks], Bv[ks][0], acc[0], 0, 0, 0);
        acc[1] = __builtin_amdgcn_mfma_f32_16x16x32_bf16(a[ks], Bv[ks][1], acc[1], 0, 0, 0);
        acc[2] = __builtin_amdgcn_mfma_f32_16x16x32_bf16(a[ks], Bv[ks][2], acc[2], 0, 0, 0);
        acc[3] = __builtin_amdgcn_mfma_f32_16x16x32_bf16(a[ks], Bv[ks][3], acc[3], 0, 0, 0);
      }
#pragma unroll
      for (int r = 0; r < 4; ++r) {
        float b1r = ((const float*)&b1v)[r];
        float w2r = ((const float*)&w2v)[r];
        float cb = C * b1r;
        float bw = b1r * w2r;
#pragma unroll
        for (int ni = 0; ni < 4; ++ni) {
          float av = acc[ni][r];
          float m = __builtin_fmaf(av, C, cb);
          float e = fast_exp2(m);
          float rr2 = fast_rcp(1.0f + e);
          float yw = __builtin_fmaf(av, w2r, bw);
          psum[1][ni] = __builtin_fmaf(yw, rr2, psum[1][ni]);
        }
      }
    }

    // pass 2: small j (js), ks unconditional (<=2 quads real)
    for (int mt = mh; mt < nt_s; mt += 2) {
      const int mo = mt * 128;
      bf16x8 a[2];
#pragma unroll
      for (int ks = 0; ks < 2; ++ks)
        a[ks] = *(const bf16x8*)(As + (ks * 4 + quad) * 1024 + mo);
      const int tb = mt * 16 + quad * 4;
      float4 b1v = *(const float4*)(b1j + js * 128 + tb);
      float4 w2v = *(const float4*)(W2j + js * 128 + tb);
      f32x4 acc[4];
#pragma unroll
      for (int ni = 0; ni < 4; ++ni) { f32x4 z = {0.f, 0.f, 0.f, 0.f}; acc[ni] = z; }
#pragma unroll
      for (int ks = 0; ks < 2; ++ks) {
        acc[0] = __builtin_amdgcn_mfma_f32_16x16x32_bf16(a[ks], Bv[ks][0], acc[0], 0, 0, 0);
        acc[1] = __builtin_amdgcn_mfma_f32_16x16x32_bf16(a[ks], Bv[ks][1], acc[1], 0, 0, 0);
        acc[2] = __builtin_amdgcn_mfma_f32_16x16x32_bf16(a[ks], Bv[ks][2], acc[2], 0, 0, 0);
        acc[3] = __builtin_amdgcn_mfma_f32_16x16x32_bf16(a[ks], Bv[ks][3], acc[3], 0, 0, 0);
      }
#pragma unroll
      for (int r = 0; r < 4; ++r) {
        float b1r = ((const float*)&b1v)[r];
        float w2r = ((const float*)&w2v)[r];
        float cb = C * b1r;
        float bw = b1r * w2r;
#pragma unroll
        for (int ni = 0; ni < 4; ++ni) {
          float av = acc[ni][r];
          float m = __builtin_fmaf(av, C, cb);
          float e = fast_exp2(m);
          float rr2 = fast_rcp(1.0f + e);
          float yw = __builtin_fmaf(av, w2r, bw);
          psum[0][ni] = __builtin_fmaf(yw, rr2, psum[0][ni]);
        }
      }
    }

    // quad reduction + stash to this g's res slice (no barrier needed yet)
#pragma unroll
    for (int jj = 0; jj < 2; ++jj)
#pragma unroll
      for (int ni = 0; ni < 4; ++ni) {
        float v = psum[jj][ni];
        v += __shfl_xor(v, 16, 64);
        v += __shfl_xor(v, 32, 64);
        psum[jj][ni] = v;
      }
    if (quad == 0) {
#pragma unroll
      for (int jj = 0; jj < 2; ++jj)
#pragma unroll
        for (int ni = 0; ni < 4; ++ni)
          res[g * 512 + wave * 128 + jj * 64 + ni * 16 + lane15] = psum[jj][ni];
    }
  }
  __syncthreads();

  // finish rows: tid = pp*128 + jj*64 + nni*16 + l ; partner at +256 (mh=1)
  {
    const int l = tid & 15;
    const int nni = (tid >> 4) & 3;
    const int jj = (tid >> 6) & 1;
    const int pp = tid >> 7;
    const int h = pp * 64 + nni * 16 + l;
#pragma unroll
    for (int g = 0; g < 4; ++g) {
      const int jp = jg * 4 + g;
      const int j = jj ? 127 - jp : jp;
      float v = res[g * 512 + tid] + res[g * 512 + tid + 256] + b2j[j] +
                trendR[(b * 128 + j) * 128 + h];
      xrow[g * 2 + jj][h] = v;  // row8 = g*2 + jj
    }
  }
  __syncthreads();

  // ---- fused MLP on 8 valid rows (A rows 8..15 replicate 0..7; unused) ----
  const int arow = lane15 & 7;
  bf16x8 af[4];
#pragma unroll
  for (int ks = 0; ks < 4; ++ks) {
    const f32x4* xp = (const f32x4*)&xrow[arow][(ks * 4 + quad) * 8];
    f32x4 v0 = xp[0], v1 = xp[1];
    unsigned short t[8] __attribute__((aligned(16)));
    t[0] = f2bf(v0[0]); t[1] = f2bf(v0[1]); t[2] = f2bf(v0[2]); t[3] = f2bf(v0[3]);
    t[4] = f2bf(v1[0]); t[5] = f2bf(v1[1]); t[6] = f2bf(v1[2]); t[7] = f2bf(v1[3]);
    af[ks] = *(const bf16x8*)t;
  }
  f32x4 acc1[2];
  { f32x4 z = {0.f, 0.f, 0.f, 0.f}; acc1[0] = z; acc1[1] = z; }
#pragma unroll
  for (int ks = 0; ks < 4; ++ks) {  // GEMM1: x @ Wm1 (cols wave*32..+31)
    int kq = ks * 4 + quad;
    bf16x8 w0 = *(const bf16x8*)(Wm1c + (kq * 128 + wave * 32 + lane15) * 8);
    bf16x8 w1 = *(const bf16x8*)(Wm1c + (kq * 128 + wave * 32 + 16 + lane15) * 8);
    acc1[0] = __builtin_amdgcn_mfma_f32_16x16x32_bf16(af[ks], w0, acc1[0], 0, 0, 0);
    acc1[1] = __builtin_amdgcn_mfma_f32_16x16x32_bf16(af[ks], w1, acc1[1], 0, 0, 0);
  }
  if (quad < 2) {  // D rows 0..7 live in quads 0,1 (row = quad*4 + r)
#pragma unroll
    for (int ni2 = 0; ni2 < 2; ++ni2) {
      int n = wave * 32 + ni2 * 16 + lane15;
      float bv = bm1[n];
#pragma unroll
      for (int r = 0; r < 4; ++r)
        urow[quad * 4 + r][n] = f2bf(gelu_f(acc1[ni2][r] + bv));
    }
  }
  __syncthreads();
  bf16x8 uf[4];
#pragma unroll
  for (int ks = 0; ks < 4; ++ks)  // A-frag rebuild from LDS (16B aligned)
    uf[ks] = *(const bf16x8*)&urow[arow][(ks * 4 + quad) * 8];
  f32x4 acc2[2];
  { f32x4 z = {0.f, 0.f, 0.f, 0.f}; acc2[0] = z; acc2[1] = z; }
#pragma unroll
  for (int ks = 0; ks < 4; ++ks) {  // GEMM2: u @ Wm2
    int kq = ks * 4 + quad;
    bf16x8 w0 = *(const bf16x8*)(Wm2c + (kq * 128 + wave * 32 + lane15) * 8);
    bf16x8 w1 = *(const bf16x8*)(Wm2c + (kq * 128 + wave * 32 + 16 + lane15) * 8);
    acc2[0] = __builtin_amdgcn_mfma_f32_16x16x32_bf16(uf[ks], w0, acc2[0], 0, 0, 0);
    acc2[1] = __builtin_amdgcn_mfma_f32_16x16x32_bf16(uf[ks], w1, acc2[1], 0, 0, 0);
  }
  if (quad < 2) {
#pragma unroll
    for (int ni2 = 0; ni2 < 2; ++ni2) {
      int n = wave * 32 + ni2 * 16 + lane15;
      float bv = bm2[n];
#pragma unroll
      for (int r = 0; r < 4; ++r) {
        int row8 = quad * 4 + r;        // = g*2 + jj
        int g = row8 >> 1, jj = row8 & 1;
        int jp = jg * 4 + g;
        int j = jj ? 127 - jp : jp;
        float v = acc2[ni2][r] + bv;
        outA[(b * 128 + j) * 128 + n] = v;
        if (outTc)  // chunks (kq_s, h) feeding the next stage's B-operand
          outTc[b * 16384 + ((j >> 3) * 128 + n) * 8 + (j & 7)] = f2bf(v);
      }
    }
  }
}

// ---------------------------------------------------------------------------
extern "C" void kernel_launch(void* const* d_in, const int* in_sizes, int n_in,
                              void* d_out, int out_size, void* d_ws, size_t ws_size,
                              hipStream_t stream) {
  (void)in_sizes; (void)n_in; (void)out_size; (void)ws_size;
  const float* trend0 = (const float*)d_in[0];
  const float* trend1 = (const float*)d_in[1];
  const float* trend2 = (const float*)d_in[2];
  const float* W1  = (const float*)d_in[3];
  const float* b1  = (const float*)d_in[4];
  const float* W2  = (const float*)d_in[5];
  const float* b2  = (const float*)d_in[6];
  const float* Wm1 = (const float*)d_in[7];
  const float* bm1 = (const float*)d_in[8];
  const float* Wm2 = (const float*)d_in[9];
  const float* bm2 = (const float*)d_in[10];
  float* out = (float*)d_out;
  char* ws = (char*)d_ws;

  unsigned short* W1Tc = (unsigned short*)(ws);             // 8.39 MB (2 stages)
  unsigned short* T2c  = (unsigned short*)(ws + 8388608);   // 1 MB
  unsigned short* A1Tc = (unsigned short*)(ws + 9437184);   // 1 MB
  unsigned short* Wm1c = (unsigned short*)(ws + 10485760);  // 32 KB
  unsigned short* Wm2c = (unsigned short*)(ws + 10518528);  // 32 KB

  // outputs: [A2 | A1 | trend2]
  prepass_kernel<<<1154, 256, 0, stream>>>(W1, trend2, Wm1, Wm2,
                                           W1Tc, T2c, Wm1c, Wm2c, out + 2 * BSH);
  // stage 0: X = trend2, residual = trend1 -> A1 (fp32 out + chunks for stage1)
  mix_mlp_kernel<<<512, 256, 0, stream>>>(T2c, W1Tc, b1, W2, b2, trend1,
                                          Wm1c, Wm2c, bm1, bm2,
                                          out + BSH, A1Tc);
  // stage 1: X = A1, residual = trend0 -> A2 (fp32 out only)
  mix_mlp_kernel<<<512, 256, 0, stream>>>(A1Tc, W1Tc + 128 * 16384, b1 + 16384,
                                          W2 + 16384, b2 + 128, trend0,
                                          Wm1c, Wm2c, bm1, bm2,
                                          out, (unsigned short*)nullptr);
}

// Round 6
// 137.769 us; speedup vs baseline: 1.3341x; 1.0588x over previous
//
#include <hip/hip_runtime.h>
#include <stdint.h>

#define BSH (32 * 128 * 128)

typedef __attribute__((ext_vector_type(8))) __bf16 bf16x8;
typedef __attribute__((ext_vector_type(4))) float f32x4;

__device__ __forceinline__ unsigned short f2bf(float f) {
  union { float f; unsigned u; } v; v.f = f;
  return (unsigned short)((v.u + 0x7FFFu + ((v.u >> 16) & 1u)) >> 16);
}

__device__ __forceinline__ float fast_exp2(float x) {
#if __has_builtin(__builtin_amdgcn_exp2f)
  return __builtin_amdgcn_exp2f(x);
#else
  float r; asm("v_exp_f32 %0, %1" : "=v"(r) : "v"(x)); return r;
#endif
}
__device__ __forceinline__ float fast_rcp(float x) {
#if __has_builtin(__builtin_amdgcn_rcpf)
  return __builtin_amdgcn_rcpf(x);
#else
  float r; asm("v_rcp_f32 %0, %1" : "=v"(r) : "v"(x)); return r;
#endif
}

// tanh-form GELU (MLP path; ~3e-3 max err vs exact erf GELU).
__device__ __forceinline__ float gelu_f(float y) {
  float u = y * y;
  float p = __builtin_fmaf(u, 0.044715f, 1.0f) * y;
  float w = fast_exp2(p * 2.30220787f);
  return y - y * fast_rcp(1.0f + w);
}

// ---------------------------------------------------------------------------
// Chunked k-major layout: tensor [row][k] stored as chunk(kq,row) =
// base + (kq*128 + row)*8 bf16 (16 B). MFMA fragment read = one
// global_load_dwordx4, 256 B contiguous per quad.
// ---------------------------------------------------------------------------
// Prepass transpose, bank-conflict-clean both sides (R9 fix, kept):
//   write: [s][t] pitch 136 u16, each thread 4 consecutive t (8 B) -> 2-way.
//   read:  16 consecutive lanes walk consecutive tr (2 B stride) -> free.
__device__ __forceinline__ void transpose_block_c(const float* __restrict__ src,
                                                  unsigned short* __restrict__ dst,
                                                  unsigned short* lds) {
  const int tid = threadIdx.x;
  const float4* s4 = (const float4*)(src);
#pragma unroll
  for (int it = 0; it < 16; ++it) {
    int i4 = tid + it * 256;
    float4 v = s4[i4];
    int s = i4 >> 5;
    int t0 = (i4 * 4) & 127;
    unsigned short* pp = lds + s * 136 + t0;
    pp[0] = f2bf(v.x); pp[1] = f2bf(v.y); pp[2] = f2bf(v.z); pp[3] = f2bf(v.w);
  }
  __syncthreads();
#pragma unroll
  for (int it = 0; it < 8; ++it) {
    int c = tid + it * 256;
    int sc = c >> 7, tr = c & 127;  // lanes walk tr -> conflict-free gather
    unsigned short tmp[8] __attribute__((aligned(16)));
#pragma unroll
    for (int e = 0; e < 8; ++e) tmp[e] = lds[(sc * 8 + e) * 136 + tr];
    *(uint4*)(dst + (sc * 128 + tr) * 8) = *(const uint4*)tmp;
  }
}

// XCD owner of j is (j<64 ? j : 127-j) & 7 -- matches mix_kernel's bid&7.
__global__ __launch_bounds__(256) void prepass_kernel(
    const float* __restrict__ W1, const float* __restrict__ trend2,
    const float* __restrict__ Wm1, const float* __restrict__ Wm2,
    unsigned short* __restrict__ W1Tc, unsigned short* __restrict__ T2c,
    unsigned short* __restrict__ Wm1c, unsigned short* __restrict__ Wm2c,
    float* __restrict__ out2) {
  __shared__ unsigned short lds[128 * 136];
  const int bid = blockIdx.x;
  if (bid < 256) {  // W1[stage][j][s][t] -> chunks (kq_s, t), XCD-pinned j map
    int x = bid & 7, i = bid >> 3;   // i 0..31
    int stage = i >> 4, u = i & 15;  // u 0..15
    int m = u & 7, half = u >> 3;
    int jpp = x + 8 * m;             // pair index owned by XCD x
    int j = half ? 127 - jpp : jpp;
    int blk = stage * 128 + j;
    transpose_block_c(W1 + blk * 16384, W1Tc + blk * 16384, lds);
  } else if (bid < 288) {  // trend2[b][s][h] -> chunks (kq_s, h) + fp32 copy
    const int b = bid - 256;
    transpose_block_c(trend2 + b * 16384, T2c + b * 16384, lds);
    const float4* s4 = (const float4*)(trend2 + b * 16384);
    float4* d4 = (float4*)(out2 + b * 16384);
#pragma unroll
    for (int it = 0; it < 16; ++it)
      d4[threadIdx.x + it * 256] = s4[threadIdx.x + it * 256];
  } else if (bid == 288) {
    transpose_block_c(Wm1, Wm1c, lds);
  } else {
    transpose_block_c(Wm2, Wm2c, lds);
  }
}

// ---------------------------------------------------------------------------
// Mix kernel v7 = R8's proven structure + mt-split across waves.
// Block = 256 threads / 4 waves: wave = (mh, p); p = h-half (B operand),
// mh = mt-parity. Each wave register-hoists B once (R8 win, 64 VGPR) and
// runs only every other m-tile -> per-wave A-loads, MFMAs, and the gelu
// epilogue all HALVE vs R8 (which duplicated the mt-loop in both waves).
// Cross-wave combine: 512-float LDS bounce + 1 barrier; writer is a
// perfect 256-thread map (v = res[tid] + res[tid+256]).
// No LDS A-staging (R9 lesson: don't trade occupancy for staging).
// ---------------------------------------------------------------------------
__global__ __launch_bounds__(256, 3) void mix_kernel(
    const unsigned short* __restrict__ XTc,   // [32] chunks (kq_s, h)
    const unsigned short* __restrict__ W1Tj,  // [128] chunks (kq_s, t), stage
    const float* __restrict__ b1j,            // [128][128] (j, t)
    const float* __restrict__ W2j,            // [128][128] (j, t)
    const float* __restrict__ b2j,            // [128]
    const float* __restrict__ trendR,         // [32][128][128] fp32 residual
    unsigned short* __restrict__ xoutc) {     // [32] chunks (kq_h, j)
  __shared__ float res[512];
  const int bid = blockIdx.x;
  const int b = bid >> 6;
  const int jp = bid & 63;       // bid&7 = jp&7 -> XCD pin matches prepass
  const int js = jp, jb = 127 - jp;
  const int tid = threadIdx.x;
  const int wave = tid >> 6;     // wave = 2*mh + p
  const int p = wave & 1;        // h-half
  const int mh = wave >> 1;      // mt parity
  const int lane = tid & 63;
  const int lane15 = lane & 15;
  const int quad = lane >> 4;

  const int nt_s = (js >> 4) + 1, ks_s = (js >> 5) + 1;  // ks_s <= 2
  const int nt_b = (jb >> 4) + 1, ks_b = (jb >> 5) + 1;  // ks_b = 3 or 4

  const unsigned short* Bp = XTc + b * 16384 + (p * 64 + lane15) * 8;
  const unsigned short* As = W1Tj + js * 16384 + lane15 * 8;
  const unsigned short* Ab = W1Tj + jb * 16384 + lane15 * 8;
  const float C = -2.45546937f;  // -1.702 * log2(e)

  // ---- hoist B-fragments (cross-XCD operand) into registers, once ----
  bf16x8 Bv[4][4];
#pragma unroll
  for (int ks = 0; ks < 4; ++ks)
    if (ks < ks_b) {
      const int ko = (ks * 4 + quad) * 1024;
      Bv[ks][0] = *(const bf16x8*)(Bp + ko);
      Bv[ks][1] = *(const bf16x8*)(Bp + ko + 128);
      Bv[ks][2] = *(const bf16x8*)(Bp + ko + 256);
      Bv[ks][3] = *(const bf16x8*)(Bp + ko + 384);
    }

  float psum[2][4];
#pragma unroll
  for (int jj = 0; jj < 2; ++jj)
#pragma unroll
    for (int ni = 0; ni < 4; ++ni) psum[jj][ni] = 0.f;

  // ---- pass 1: big j (jb), this wave's mt-parity only ----
  for (int mt = mh; mt < nt_b; mt += 2) {
    f32x4 acc[4];
#pragma unroll
    for (int ni = 0; ni < 4; ++ni) { f32x4 z = {0.f, 0.f, 0.f, 0.f}; acc[ni] = z; }
    const int mo = mt * 128;
#pragma unroll
    for (int ks = 0; ks < 4; ++ks)
      if (ks < ks_b) {
        bf16x8 a = *(const bf16x8*)(Ab + (ks * 4 + quad) * 1024 + mo);
        acc[0] = __builtin_amdgcn_mfma_f32_16x16x32_bf16(a, Bv[ks][0], acc[0], 0, 0, 0);
        acc[1] = __builtin_amdgcn_mfma_f32_16x16x32_bf16(a, Bv[ks][1], acc[1], 0, 0, 0);
        acc[2] = __builtin_amdgcn_mfma_f32_16x16x32_bf16(a, Bv[ks][2], acc[2], 0, 0, 0);
        acc[3] = __builtin_amdgcn_mfma_f32_16x16x32_bf16(a, Bv[ks][3], acc[3], 0, 0, 0);
      }
    const int tb = mt * 16 + quad * 4;
    float4 b1v = *(const float4*)(b1j + jb * 128 + tb);
    float4 w2v = *(const float4*)(W2j + jb * 128 + tb);
#pragma unroll
    for (int r = 0; r < 4; ++r) {
      float b1r = ((const float*)&b1v)[r];
      float w2r = ((const float*)&w2v)[r];
      float cb = C * b1r;
      float bw = b1r * w2r;
#pragma unroll
      for (int ni = 0; ni < 4; ++ni) {
        float a = acc[ni][r];
        float m = __builtin_fmaf(a, C, cb);
        float e = fast_exp2(m);
        float rr2 = fast_rcp(1.0f + e);
        float yw = __builtin_fmaf(a, w2r, bw);
        psum[1][ni] = __builtin_fmaf(yw, rr2, psum[1][ni]);
      }
    }
  }

  // ---- pass 2: small j (js), B already in registers ----
  for (int mt = mh; mt < nt_s; mt += 2) {
    f32x4 acc[4];
#pragma unroll
    for (int ni = 0; ni < 4; ++ni) { f32x4 z = {0.f, 0.f, 0.f, 0.f}; acc[ni] = z; }
    const int mo = mt * 128;
#pragma unroll
    for (int ks = 0; ks < 2; ++ks)  // ks_s <= 2 for js < 64
      if (ks < ks_s) {
        bf16x8 a = *(const bf16x8*)(As + (ks * 4 + quad) * 1024 + mo);
        acc[0] = __builtin_amdgcn_mfma_f32_16x16x32_bf16(a, Bv[ks][0], acc[0], 0, 0, 0);
        acc[1] = __builtin_amdgcn_mfma_f32_16x16x32_bf16(a, Bv[ks][1], acc[1], 0, 0, 0);
        acc[2] = __builtin_amdgcn_mfma_f32_16x16x32_bf16(a, Bv[ks][2], acc[2], 0, 0, 0);
        acc[3] = __builtin_amdgcn_mfma_f32_16x16x32_bf16(a, Bv[ks][3], acc[3], 0, 0, 0);
      }
    const int tb = mt * 16 + quad * 4;
    float4 b1v = *(const float4*)(b1j + js * 128 + tb);
    float4 w2v = *(const float4*)(W2j + js * 128 + tb);
#pragma unroll
    for (int r = 0; r < 4; ++r) {
      float b1r = ((const float*)&b1v)[r];
      float w2r = ((const float*)&w2v)[r];
      float cb = C * b1r;
      float bw = b1r * w2r;
#pragma unroll
      for (int ni = 0; ni < 4; ++ni) {
        float a = acc[ni][r];
        float m = __builtin_fmaf(a, C, cb);
        float e = fast_exp2(m);
        float rr2 = fast_rcp(1.0f + e);
        float yw = __builtin_fmaf(a, w2r, bw);
        psum[0][ni] = __builtin_fmaf(yw, rr2, psum[0][ni]);
      }
    }
  }

  // quad reduction (sum over the 4 t-rows held across quads)
#pragma unroll
  for (int jj = 0; jj < 2; ++jj)
#pragma unroll
    for (int ni = 0; ni < 4; ++ni) {
      float v = psum[jj][ni];
      v += __shfl_xor(v, 16, 64);
      v += __shfl_xor(v, 32, 64);
      psum[jj][ni] = v;
    }

  // cross-wave (mt-parity) combine via LDS: idx = wave*128 + jj*64 + ni*16 + l
  if (quad == 0) {
#pragma unroll
    for (int jj = 0; jj < 2; ++jj)
#pragma unroll
      for (int ni = 0; ni < 4; ++ni)
        res[wave * 128 + jj * 64 + ni * 16 + lane15] = psum[jj][ni];
  }
  __syncthreads();
  {
    // tid = p*128 + jj*64 + ni*16 + l  ->  partner at tid + 256 (mh=1)
    const int l = tid & 15;
    const int ni = (tid >> 4) & 3;
    const int jj = (tid >> 6) & 1;
    const int pp = tid >> 7;
    const int j = jj ? jb : js;
    const int h = pp * 64 + ni * 16 + l;
    float v = res[tid] + res[tid + 256] + b2j[j] +
              trendR[(b * 128 + j) * 128 + h];
    xoutc[b * 16384 + ((h >> 3) * 128 + j) * 8 + (h & 7)] = f2bf(v);
  }
}

// ---------------------------------------------------------------------------
// MLP kernel (known-good from R3): grid 256 = 32 b x 8 tiles of 16 rows.
// ---------------------------------------------------------------------------
__global__ __launch_bounds__(256) void mlp_kernel(
    const unsigned short* __restrict__ Xc,    // [32] chunks (kq_h, j)
    const unsigned short* __restrict__ Wm1c,  // chunks (kq_in, out)
    const unsigned short* __restrict__ Wm2c,
    const float* __restrict__ bm1,
    const float* __restrict__ bm2,
    float* __restrict__ outf,                 // [32][128][128] fp32
    unsigned short* __restrict__ outTc,       // [32] chunks (kq_s, h), optional
    const int write_t) {
  __shared__ __align__(16) unsigned short U[16 * 128];  // chunks (kq_h, row16)
  __shared__ unsigned short ldsT[16 * 136];
  const int bid = blockIdx.x;
  const int b = bid >> 3;
  const int mb = bid & 7;
  const int tid = threadIdx.x;
  const int wave = tid >> 6;
  const int lane = tid & 63;
  const int lane15 = lane & 15;
  const int quad = lane >> 4;

  const unsigned short* Xb = Xc + b * 16384;

  f32x4 acc[2];
  { f32x4 z = {0.f, 0.f, 0.f, 0.f}; acc[0] = z; acc[1] = z; }
#pragma unroll
  for (int ks = 0; ks < 4; ++ks) {  // GEMM1: x @ Wm1
    int kq = ks * 4 + quad;
    bf16x8 a  = *(const bf16x8*)(Xb + (kq * 128 + mb * 16 + lane15) * 8);
    bf16x8 w0 = *(const bf16x8*)(Wm1c + (kq * 128 + wave * 32 + lane15) * 8);
    bf16x8 w1 = *(const bf16x8*)(Wm1c + (kq * 128 + wave * 32 + 16 + lane15) * 8);
    acc[0] = __builtin_amdgcn_mfma_f32_16x16x32_bf16(a, w0, acc[0], 0, 0, 0);
    acc[1] = __builtin_amdgcn_mfma_f32_16x16x32_bf16(a, w1, acc[1], 0, 0, 0);
  }
#pragma unroll
  for (int ni = 0; ni < 2; ++ni) {  // bias+gelu -> U (A-layout for GEMM2)
    int n = wave * 32 + ni * 16 + lane15;
    float bv = bm1[n];
#pragma unroll
    for (int r = 0; r < 4; ++r) {
      int jr = quad * 4 + r;
      U[((n >> 3) * 16 + jr) * 8 + (n & 7)] = f2bf(gelu_f(acc[ni][r] + bv));
    }
  }
  __syncthreads();
  { f32x4 z = {0.f, 0.f, 0.f, 0.f}; acc[0] = z; acc[1] = z; }
#pragma unroll
  for (int ks = 0; ks < 4; ++ks) {  // GEMM2: u @ Wm2
    int kq = ks * 4 + quad;
    bf16x8 a  = *(const bf16x8*)(U + (kq * 16 + lane15) * 8);
    bf16x8 w0 = *(const bf16x8*)(Wm2c + (kq * 128 + wave * 32 + lane15) * 8);
    bf16x8 w1 = *(const bf16x8*)(Wm2c + (kq * 128 + wave * 32 + 16 + lane15) * 8);
    acc[0] = __builtin_amdgcn_mfma_f32_16x16x32_bf16(a, w0, acc[0], 0, 0, 0);
    acc[1] = __builtin_amdgcn_mfma_f32_16x16x32_bf16(a, w1, acc[1], 0, 0, 0);
  }
  {
    float* outb = outf + b * 16384 + mb * 16 * 128;
#pragma unroll
    for (int ni = 0; ni < 2; ++ni) {
      int n = wave * 32 + ni * 16 + lane15;
      float bv = bm2[n];
#pragma unroll
      for (int r = 0; r < 4; ++r) {
        int jr = quad * 4 + r;
        float v = acc[ni][r] + bv;
        outb[jr * 128 + n] = v;
        if (write_t) ldsT[jr * 136 + n] = f2bf(v);
      }
    }
  }
  if (write_t) {  // emit chunks (kq_s, h) for the next mix stage's B-operand
    __syncthreads();
    int h = tid & 127, jr8 = tid >> 7;
    unsigned short tmp[8] __attribute__((aligned(16)));
#pragma unroll
    for (int e = 0; e < 8; ++e) tmp[e] = ldsT[(jr8 * 8 + e) * 136 + h];
    *(uint4*)(outTc + b * 16384 + ((mb * 2 + jr8) * 128 + h) * 8) = *(const uint4*)tmp;
  }
}

// ---------------------------------------------------------------------------
extern "C" void kernel_launch(void* const* d_in, const int* in_sizes, int n_in,
                              void* d_out, int out_size, void* d_ws, size_t ws_size,
                              hipStream_t stream) {
  (void)in_sizes; (void)n_in; (void)out_size; (void)ws_size;
  const float* trend0 = (const float*)d_in[0];
  const float* trend1 = (const float*)d_in[1];
  const float* trend2 = (const float*)d_in[2];
  const float* W1  = (const float*)d_in[3];
  const float* b1  = (const float*)d_in[4];
  const float* W2  = (const float*)d_in[5];
  const float* b2  = (const float*)d_in[6];
  const float* Wm1 = (const float*)d_in[7];
  const float* bm1 = (const float*)d_in[8];
  const float* Wm2 = (const float*)d_in[9];
  const float* bm2 = (const float*)d_in[10];
  float* out = (float*)d_out;
  char* ws = (char*)d_ws;

  unsigned short* W1Tc = (unsigned short*)(ws);             // 8.39 MB (2 stages)
  unsigned short* T2c  = (unsigned short*)(ws + 8388608);   // 1 MB
  unsigned short* x1c  = (unsigned short*)(ws + 9437184);   // 1 MB
  unsigned short* A1Tc = (unsigned short*)(ws + 10485760);  // 1 MB
  unsigned short* x2c  = (unsigned short*)(ws + 11534336);  // 1 MB
  unsigned short* Wm1c = (unsigned short*)(ws + 12582912);  // 32 KB
  unsigned short* Wm2c = (unsigned short*)(ws + 12615680);  // 32 KB

  // outputs: [A2 | A1 | trend2]
  prepass_kernel<<<290, 256, 0, stream>>>(W1, trend2, Wm1, Wm2,
                                          W1Tc, T2c, Wm1c, Wm2c, out + 2 * BSH);
  // stage 0: X = trend2, residual = trend1 -> x1 (bf16 chunks)
  mix_kernel<<<2048, 256, 0, stream>>>(T2c, W1Tc, b1, W2, b2, trend1, x1c);
  // A1 = mlp(x1) -> d_out[1] + A1Tc chunks (next stage's B operand)
  mlp_kernel<<<256, 256, 0, stream>>>(x1c, Wm1c, Wm2c, bm1, bm2,
                                      out + BSH, A1Tc, 1);
  // stage 1: X = A1, residual = trend0 -> x2
  mix_kernel<<<2048, 256, 0, stream>>>(A1Tc, W1Tc + 128 * 16384, b1 + 16384,
                                       W2 + 16384, b2 + 128, trend0, x2c);
  // A2 = mlp(x2) -> d_out[0]
  mlp_kernel<<<256, 256, 0, stream>>>(x2c, Wm1c, Wm2c, bm1, bm2,
                                      out, (unsigned short*)nullptr, 0);
}